// Round 1
// baseline (1207.763 us; speedup 1.0000x reference)
//
#include <hip/hip_runtime.h>

#define N_NODESC 200000
#define N_EDGESC 3200000
#define N_GRAPHSC 2000
#define NMAXG 256
#define TOPK 30
#define DCAT 97
#define POOLW (TOPK*DCAT) /* 2910 */

__global__ void k_count(const int* __restrict__ src, const int* __restrict__ dst, int* __restrict__ cnt){
  int e = blockIdx.x*256 + threadIdx.x;
  if (e < N_EDGESC){ int s=src[e], d=dst[e]; if (s!=d) atomicAdd(&cnt[d],1); }
}

__global__ void k_bhist(const int* __restrict__ batch, int* __restrict__ gcount){
  int i = blockIdx.x*256 + threadIdx.x;
  if (i < N_NODESC) atomicAdd(&gcount[batch[i]],1);
}

__global__ __launch_bounds__(1024) void k_scan1(const int* __restrict__ in, int* __restrict__ excl, int* __restrict__ bsum, int n){
  __shared__ int sm[1024];
  int t = threadIdx.x;
  int i = blockIdx.x*1024 + t;
  int v = (i<n)? in[i] : 0;
  sm[t]=v; __syncthreads();
  for (int off=1; off<1024; off<<=1){
    int u = (t>=off)? sm[t-off] : 0;
    __syncthreads();
    sm[t] += u;
    __syncthreads();
  }
  if (i<n) excl[i] = sm[t]-v;
  if (t==1023) bsum[blockIdx.x] = sm[1023];
}

__global__ __launch_bounds__(256) void k_scan2(int* __restrict__ bsum, int nb){
  __shared__ int sm[256];
  int t=threadIdx.x;
  int v = (t<nb)? bsum[t] : 0;
  sm[t]=v; __syncthreads();
  for(int off=1; off<256; off<<=1){
    int u = (t>=off)? sm[t-off] : 0;
    __syncthreads();
    sm[t]+=u;
    __syncthreads();
  }
  if (t<nb) bsum[t] = sm[t]-v;
}

__global__ __launch_bounds__(1024) void k_scan3(int* __restrict__ excl, const int* __restrict__ bsum, int n){
  int i = blockIdx.x*1024 + threadIdx.x;
  if (i<n) excl[i] += bsum[blockIdx.x];
}

__global__ void k_dis(const int* __restrict__ cnt, float* __restrict__ dis){
  int i = blockIdx.x*256+threadIdx.x;
  if (i<N_NODESC) dis[i] = rsqrtf((float)cnt[i] + 1.0f);
}

__global__ void k_fill(const int* __restrict__ src, const int* __restrict__ dst, const int* __restrict__ off, int* __restrict__ fptr, int* __restrict__ csr){
  int e = blockIdx.x*256+threadIdx.x;
  if (e<N_EDGESC){
    int s=src[e], d=dst[e];
    if (s!=d){ int p=atomicAdd(&fptr[d],1); csr[off[d]+p]=s; }
  }
}

template<int KIN>
__global__ __launch_bounds__(256) void k_mm(const float* __restrict__ X, const float* __restrict__ W, float* __restrict__ out){
  __shared__ float Ws[KIN*32];
  for (int i=threadIdx.x;i<KIN*32;i+=256) Ws[i]=W[i];
  __syncthreads();
  int r = blockIdx.x*8 + (threadIdx.x>>5);
  if (r>=N_NODESC) return;
  int f = threadIdx.x&31;
  const float* xr = X + (size_t)r*KIN;
  float acc=0.f;
  #pragma unroll
  for (int k=0;k<KIN;k++) acc = fmaf(xr[k], Ws[k*32+f], acc);
  out[(size_t)r*32+f]=acc;
}

__global__ void k_mm4(const float* __restrict__ X, const float* __restrict__ W, float* __restrict__ out){
  int r = blockIdx.x*256+threadIdx.x;
  if (r>=N_NODESC) return;
  const float4* xr = (const float4*)(X + (size_t)r*32);
  float acc=0.f;
  #pragma unroll
  for (int k4=0;k4<8;k4++){
    float4 xv = xr[k4];
    acc = fmaf(xv.x, W[k4*4+0], acc);
    acc = fmaf(xv.y, W[k4*4+1], acc);
    acc = fmaf(xv.z, W[k4*4+2], acc);
    acc = fmaf(xv.w, W[k4*4+3], acc);
  }
  out[r]=acc;
}

__global__ __launch_bounds__(256) void k_agg(const float* __restrict__ hw, const int* __restrict__ csr,
                      const int* __restrict__ off, const int* __restrict__ cnt,
                      const float* __restrict__ dis, const float* __restrict__ bias,
                      float* __restrict__ out){
  int t = blockIdx.x*256 + threadIdx.x;
  int n = t>>5;
  if (n>=N_NODESC) return;
  int f = t&31;
  int beg = off[n], c = cnt[n];
  float acc=0.f;
  for (int e=0;e<c;e++){
    int s = csr[beg+e];
    acc = fmaf(hw[(size_t)s*32+f], dis[s], acc);
  }
  float dn = dis[n];
  float v = dn*acc + hw[(size_t)n*32+f]*dn*dn + bias[f];
  out[(size_t)n*32+f] = tanhf(v);
}

__global__ void k_agg4(const float* __restrict__ hw4, const int* __restrict__ csr,
                       const int* __restrict__ off, const int* __restrict__ cnt,
                       const float* __restrict__ dis, const float* __restrict__ b4,
                       float* __restrict__ x4){
  int n = blockIdx.x*256+threadIdx.x;
  if (n>=N_NODESC) return;
  int beg=off[n], c=cnt[n];
  float acc=0.f;
  for (int e=0;e<c;e++){ int s=csr[beg+e]; acc = fmaf(hw4[s], dis[s], acc); }
  float dn=dis[n];
  x4[n] = tanhf(dn*acc + hw4[n]*dn*dn + b4[0]);
}

__global__ __launch_bounds__(256) void k_sortpool(const float* __restrict__ x1,const float* __restrict__ x2,const float* __restrict__ x3,const float* __restrict__ x4,
                           const int* __restrict__ gcount, const int* __restrict__ goff, float* __restrict__ pool){
  __shared__ float vals[NMAXG];
  __shared__ int sel[TOPK];
  int g = blockIdx.x;
  int start = goff[g];
  int cntg = gcount[g]; if (cntg>NMAXG) cntg=NMAXG;
  int t = threadIdx.x;
  float v = 0.f;
  if (t<cntg) v = x4[start+t];
  vals[t] = v;
  __syncthreads();
  if (t<cntg){
    int rank=0;
    for (int j=0;j<cntg;j++){
      float vj=vals[j];
      rank += (vj>v) || (vj==v && j<t);
    }
    if (rank<TOPK) sel[rank]=t;
  }
  __syncthreads();
  int nsel = cntg<TOPK?cntg:TOPK;
  float* pg = pool + (size_t)g*POOLW;
  for (int idx=t; idx<POOLW; idx+=256){
    int r = idx/DCAT, c = idx - r*DCAT;
    float val=0.f;
    if (r<nsel){
      int node = start + sel[r];
      if (c<32) val = x1[(size_t)node*32+c];
      else if (c<64) val = x2[(size_t)node*32+(c-32)];
      else if (c<96) val = x3[(size_t)node*32+(c-64)];
      else val = x4[node];
    }
    pg[idx]=val;
  }
}

__global__ __launch_bounds__(128) void k_head(const float* __restrict__ pool,
                       const float* __restrict__ cw5, const float* __restrict__ cb5,
                       const float* __restrict__ cw6, const float* __restrict__ cb6,
                       const float* __restrict__ fw1, const float* __restrict__ fb1,
                       const float* __restrict__ fw2, const float* __restrict__ fb2,
                       float* __restrict__ out){
  __shared__ float P[POOLW];
  __shared__ float o5[16*30];
  __shared__ float m[16*15];
  __shared__ float o6[32*11];
  __shared__ float o1[128];
  __shared__ float logits[10];
  int g=blockIdx.x, t=threadIdx.x;
  const float* pg = pool + (size_t)g*POOLW;
  for (int i=t;i<POOLW;i+=128) P[i]=pg[i];
  __syncthreads();
  for (int i=t;i<480;i+=128){
    int o=i/30, k=i-o*30;
    float acc=cb5[o];
    const float* w=cw5+o*97;
    const float* p=P+k*97;
    for(int c=0;c<97;c++) acc = fmaf(p[c], w[c], acc);
    o5[o*30+k]=fmaxf(acc,0.f);
  }
  __syncthreads();
  for (int i=t;i<240;i+=128){
    int o=i/15,k=i-o*15;
    m[i]=fmaxf(o5[o*30+2*k], o5[o*30+2*k+1]);
  }
  __syncthreads();
  for (int i=t;i<352;i+=128){
    int o2=i/11, k=i-o2*11;
    float acc=cb6[o2];
    const float* w=cw6+o2*80;
    #pragma unroll
    for(int ii=0;ii<16;ii++)
      #pragma unroll
      for(int r=0;r<5;r++)
        acc = fmaf(m[ii*15+k+r], w[ii*5+r], acc);
    o6[o2*11+k]=fmaxf(acc,0.f);
  }
  __syncthreads();
  {
    float acc=fb1[t];
    for(int i=0;i<352;i++) acc = fmaf(o6[i], fw1[i*128+t], acc);
    o1[t]=fmaxf(acc,0.f);
  }
  __syncthreads();
  if (t<10){
    float acc=fb2[t];
    for(int j=0;j<128;j++) acc = fmaf(o1[j], fw2[j*10+t], acc);
    logits[t]=acc;
  }
  __syncthreads();
  if (t==0){
    float mx=logits[0];
    for(int c=1;c<10;c++) mx=fmaxf(mx,logits[c]);
    float s=0.f;
    for(int c=0;c<10;c++) s+=expf(logits[c]-mx);
    float lse=logf(s)+mx;
    for(int c=0;c<10;c++) out[(size_t)g*10+c]=logits[c]-lse;
  }
}

extern "C" void kernel_launch(void* const* d_in, const int* in_sizes, int n_in,
                              void* d_out, int out_size, void* d_ws, size_t ws_size,
                              hipStream_t stream){
  const float* x    = (const float*)d_in[0];
  const int*   ei   = (const int*)d_in[1];
  const int*   batch= (const int*)d_in[2];
  const float* W1=(const float*)d_in[3]; const float* b1=(const float*)d_in[4];
  const float* W2=(const float*)d_in[5]; const float* b2=(const float*)d_in[6];
  const float* W3=(const float*)d_in[7]; const float* b3=(const float*)d_in[8];
  const float* W4=(const float*)d_in[9]; const float* b4=(const float*)d_in[10];
  const float* cw5=(const float*)d_in[11]; const float* cb5=(const float*)d_in[12];
  const float* cw6=(const float*)d_in[13]; const float* cb6=(const float*)d_in[14];
  const float* fw1=(const float*)d_in[15]; const float* fb1=(const float*)d_in[16];
  const float* fw2=(const float*)d_in[17]; const float* fb2=(const float*)d_in[18];
  float* out=(float*)d_out;
  const int* src = ei;
  const int* dst = ei + N_EDGESC;

  char* ws=(char*)d_ws;
  size_t o=0;
  auto alloc=[&](size_t nbytes)->char*{ char* p=ws+o; o += (nbytes+255)&~(size_t)255; return p; };
  float* dis    = (float*)alloc((size_t)N_NODESC*4);
  int*   offs   = (int*)alloc((size_t)N_NODESC*4);
  int*   degc   = (int*)alloc((size_t)N_NODESC*4);
  int*   fptr   = (int*)alloc((size_t)N_NODESC*4);
  int*   bsumA  = (int*)alloc(256*4);
  int*   bsumB  = (int*)alloc(256*4);
  int*   gcount = (int*)alloc((size_t)N_GRAPHSC*4);
  int*   goff   = (int*)alloc((size_t)N_GRAPHSC*4);
  int*   csr    = (int*)alloc((size_t)N_EDGESC*4);
  float* x1 = (float*)alloc((size_t)N_NODESC*32*4);
  float* x2 = (float*)alloc((size_t)N_NODESC*32*4);
  float* x3 = (float*)alloc((size_t)N_NODESC*32*4);
  float* x4 = (float*)alloc((size_t)N_NODESC*4);
  float* hw = (float*)alloc((size_t)N_NODESC*32*4);
  float* pool = hw; /* reuse: pool written only after hw fully consumed */

  hipMemsetAsync(degc, 0, (size_t)N_NODESC*4, stream);
  hipMemsetAsync(fptr, 0, (size_t)N_NODESC*4, stream);
  hipMemsetAsync(gcount, 0, (size_t)N_GRAPHSC*4, stream);

  int gE = (N_EDGESC+255)/256;
  int gN = (N_NODESC+255)/256;
  k_count<<<gE,256,0,stream>>>(src,dst,degc);
  k_bhist<<<gN,256,0,stream>>>(batch,gcount);
  int nb1=(N_NODESC+1023)/1024;
  k_scan1<<<nb1,1024,0,stream>>>(degc,offs,bsumA,N_NODESC);
  k_scan2<<<1,256,0,stream>>>(bsumA,nb1);
  k_scan3<<<nb1,1024,0,stream>>>(offs,bsumA,N_NODESC);
  int nb2=(N_GRAPHSC+1023)/1024;
  k_scan1<<<nb2,1024,0,stream>>>(gcount,goff,bsumB,N_GRAPHSC);
  k_scan2<<<1,256,0,stream>>>(bsumB,nb2);
  k_scan3<<<nb2,1024,0,stream>>>(goff,bsumB,N_GRAPHSC);
  k_dis<<<gN,256,0,stream>>>(degc,dis);
  k_fill<<<gE,256,0,stream>>>(src,dst,offs,fptr,csr);

  int gMM=(N_NODESC+7)/8;
  k_mm<128><<<gMM,256,0,stream>>>(x, W1, hw);
  k_agg<<<gMM,256,0,stream>>>(hw,csr,offs,degc,dis,b1,x1);
  k_mm<32><<<gMM,256,0,stream>>>(x1, W2, hw);
  k_agg<<<gMM,256,0,stream>>>(hw,csr,offs,degc,dis,b2,x2);
  k_mm<32><<<gMM,256,0,stream>>>(x2, W3, hw);
  k_agg<<<gMM,256,0,stream>>>(hw,csr,offs,degc,dis,b3,x3);
  k_mm4<<<gN,256,0,stream>>>(x3, W4, hw);
  k_agg4<<<gN,256,0,stream>>>(hw,csr,offs,degc,dis,b4,x4);

  k_sortpool<<<N_GRAPHSC,256,0,stream>>>(x1,x2,x3,x4,gcount,goff,pool);
  k_head<<<N_GRAPHSC,128,0,stream>>>(pool,cw5,cb5,cw6,cb6,fw1,fb1,fw2,fb2,out);
}

// Round 2
// 944.220 us; speedup vs baseline: 1.2791x; 1.2791x over previous
//
#include <hip/hip_runtime.h>

#define N_NODESC 200000
#define N_EDGESC 3200000
#define N_GRAPHSC 2000
#define NMAXG 256
#define TOPK 30
#define DCAT 97
#define POOLW (TOPK*DCAT) /* 2910 */
#define NRANGE 8
#define RANGEW (N_NODESC/NRANGE) /* 25000 */
#define CHUNKE 8192
#define NCHUNK ((N_EDGESC+CHUNKE-1)/CHUNKE) /* 391 */

__global__ __launch_bounds__(256) void k_count(const int* __restrict__ src, const int* __restrict__ dst, int* __restrict__ cnt){
  int b = blockIdx.x; int r = b & (NRANGE-1); int chunk = b >> 3;
  int lo = r*RANGEW, hi = lo + RANGEW;
  int e0 = chunk*CHUNKE;
  int e1 = e0 + CHUNKE; if (e1 > N_EDGESC) e1 = N_EDGESC;
  for (int base = e0; base < e1; base += 1024){
    int e = base + threadIdx.x*4;
    int4 d4 = *(const int4*)(dst+e);
    int4 s4 = *(const int4*)(src+e);
    if (d4.x>=lo && d4.x<hi && s4.x!=d4.x) atomicAdd(&cnt[d4.x],1);
    if (d4.y>=lo && d4.y<hi && s4.y!=d4.y) atomicAdd(&cnt[d4.y],1);
    if (d4.z>=lo && d4.z<hi && s4.z!=d4.z) atomicAdd(&cnt[d4.z],1);
    if (d4.w>=lo && d4.w<hi && s4.w!=d4.w) atomicAdd(&cnt[d4.w],1);
  }
}

__global__ __launch_bounds__(256) void k_fill(const int* __restrict__ src, const int* __restrict__ dst, int* __restrict__ fptr, int* __restrict__ csr){
  int b = blockIdx.x; int r = b & (NRANGE-1); int chunk = b >> 3;
  int lo = r*RANGEW, hi = lo + RANGEW;
  int e0 = chunk*CHUNKE;
  int e1 = e0 + CHUNKE; if (e1 > N_EDGESC) e1 = N_EDGESC;
  for (int base = e0; base < e1; base += 1024){
    int e = base + threadIdx.x*4;
    int4 d4 = *(const int4*)(dst+e);
    int4 s4 = *(const int4*)(src+e);
    if (d4.x>=lo && d4.x<hi && s4.x!=d4.x){ int p=atomicAdd(&fptr[d4.x],1); csr[p]=s4.x; }
    if (d4.y>=lo && d4.y<hi && s4.y!=d4.y){ int p=atomicAdd(&fptr[d4.y],1); csr[p]=s4.y; }
    if (d4.z>=lo && d4.z<hi && s4.z!=d4.z){ int p=atomicAdd(&fptr[d4.z],1); csr[p]=s4.z; }
    if (d4.w>=lo && d4.w<hi && s4.w!=d4.w){ int p=atomicAdd(&fptr[d4.w],1); csr[p]=s4.w; }
  }
}

__global__ void k_bhist(const int* __restrict__ batch, int* __restrict__ gcount){
  int i = blockIdx.x*256 + threadIdx.x;
  if (i < N_NODESC) atomicAdd(&gcount[batch[i]],1);
}

__global__ __launch_bounds__(1024) void k_scan1(const int* __restrict__ in, int* __restrict__ excl, int* __restrict__ bsum, int n){
  __shared__ int sm[1024];
  int t = threadIdx.x;
  int i = blockIdx.x*1024 + t;
  int v = (i<n)? in[i] : 0;
  sm[t]=v; __syncthreads();
  for (int off=1; off<1024; off<<=1){
    int u = (t>=off)? sm[t-off] : 0;
    __syncthreads();
    sm[t] += u;
    __syncthreads();
  }
  if (i<n) excl[i] = sm[t]-v;
  if (t==1023) bsum[blockIdx.x] = sm[1023];
}

__global__ __launch_bounds__(256) void k_scan2(int* __restrict__ bsum, int nb){
  __shared__ int sm[256];
  int t=threadIdx.x;
  int v = (t<nb)? bsum[t] : 0;
  sm[t]=v; __syncthreads();
  for(int off=1; off<256; off<<=1){
    int u = (t>=off)? sm[t-off] : 0;
    __syncthreads();
    sm[t]+=u;
    __syncthreads();
  }
  if (t<nb) bsum[t] = sm[t]-v;
}

__global__ __launch_bounds__(1024) void k_scan3(int* __restrict__ excl, const int* __restrict__ bsum, int n){
  int i = blockIdx.x*1024 + threadIdx.x;
  if (i<n) excl[i] += bsum[blockIdx.x];
}

/* dis = rsqrt(deg+1); fptr = offs (so atomicAdd gives absolute csr slot) */
__global__ void k_dis(const int* __restrict__ cnt, const int* __restrict__ offs, float* __restrict__ dis, int* __restrict__ fptr){
  int i = blockIdx.x*256+threadIdx.x;
  if (i<N_NODESC){ dis[i] = rsqrtf((float)cnt[i] + 1.0f); fptr[i] = offs[i]; }
}

/* out[r][f] = (X[r] @ W)[f] * dis[r]   (pre-scaled by source-side norm) */
template<int KIN>
__global__ __launch_bounds__(256) void k_mm(const float* __restrict__ X, const float* __restrict__ W, const float* __restrict__ dis, float* __restrict__ out){
  __shared__ float Ws[KIN*32];
  for (int i=threadIdx.x;i<KIN*32;i+=256) Ws[i]=W[i];
  __syncthreads();
  int r = blockIdx.x*8 + (threadIdx.x>>5);
  if (r>=N_NODESC) return;
  int f = threadIdx.x&31;
  const float* xr = X + (size_t)r*KIN;
  float acc=0.f;
  #pragma unroll
  for (int k=0;k<KIN;k++) acc = fmaf(xr[k], Ws[k*32+f], acc);
  out[(size_t)r*32+f]=acc*dis[r];
}

__global__ void k_mm4(const float* __restrict__ X, const float* __restrict__ W, const float* __restrict__ dis, float* __restrict__ out){
  int r = blockIdx.x*256+threadIdx.x;
  if (r>=N_NODESC) return;
  const float4* xr = (const float4*)(X + (size_t)r*32);
  float acc=0.f;
  #pragma unroll
  for (int k4=0;k4<8;k4++){
    float4 xv = xr[k4];
    acc = fmaf(xv.x, W[k4*4+0], acc);
    acc = fmaf(xv.y, W[k4*4+1], acc);
    acc = fmaf(xv.z, W[k4*4+2], acc);
    acc = fmaf(xv.w, W[k4*4+3], acc);
  }
  out[r]=acc*dis[r];
}

/* x_out[n][f] = tanh( dis[n]*(sum_src hws[src][f] + hws[n][f]) + b[f] ) */
__global__ __launch_bounds__(256) void k_agg(const float* __restrict__ hws, const int* __restrict__ csr,
                      const int* __restrict__ off, const int* __restrict__ cnt,
                      const float* __restrict__ dis, const float* __restrict__ bias,
                      float* __restrict__ out){
  int t = blockIdx.x*256 + threadIdx.x;
  int n = t>>5;
  if (n>=N_NODESC) return;
  int f = t&31;
  int beg = off[n], c = cnt[n];
  float acc0=0.f, acc1=0.f;
  int e=0;
  for (; e+1<c; e+=2){
    int s0 = csr[beg+e];
    int s1 = csr[beg+e+1];
    acc0 += hws[(size_t)s0*32+f];
    acc1 += hws[(size_t)s1*32+f];
  }
  if (e<c) acc0 += hws[(size_t)csr[beg+e]*32+f];
  float dn = dis[n];
  float v = dn*(acc0+acc1+hws[(size_t)n*32+f]) + bias[f];
  out[(size_t)n*32+f] = tanhf(v);
}

__global__ void k_agg4(const float* __restrict__ hws4, const int* __restrict__ csr,
                       const int* __restrict__ off, const int* __restrict__ cnt,
                       const float* __restrict__ dis, const float* __restrict__ b4,
                       float* __restrict__ x4){
  int n = blockIdx.x*256+threadIdx.x;
  if (n>=N_NODESC) return;
  int beg=off[n], c=cnt[n];
  float acc0=0.f, acc1=0.f;
  int e=0;
  for (; e+1<c; e+=2){ acc0 += hws4[csr[beg+e]]; acc1 += hws4[csr[beg+e+1]]; }
  if (e<c) acc0 += hws4[csr[beg+e]];
  float dn=dis[n];
  x4[n] = tanhf(dn*(acc0+acc1+hws4[n]) + b4[0]);
}

__global__ __launch_bounds__(256) void k_sortpool(const float* __restrict__ x1,const float* __restrict__ x2,const float* __restrict__ x3,const float* __restrict__ x4,
                           const int* __restrict__ gcount, const int* __restrict__ goff, float* __restrict__ pool){
  __shared__ float vals[NMAXG];
  __shared__ int sel[TOPK];
  int g = blockIdx.x;
  int start = goff[g];
  int cntg = gcount[g]; if (cntg>NMAXG) cntg=NMAXG;
  int t = threadIdx.x;
  float v = 0.f;
  if (t<cntg) v = x4[start+t];
  vals[t] = v;
  __syncthreads();
  if (t<cntg){
    int rank=0;
    for (int j=0;j<cntg;j++){
      float vj=vals[j];
      rank += (vj>v) || (vj==v && j<t);
    }
    if (rank<TOPK) sel[rank]=t;
  }
  __syncthreads();
  int nsel = cntg<TOPK?cntg:TOPK;
  float* pg = pool + (size_t)g*POOLW;
  for (int idx=t; idx<POOLW; idx+=256){
    int r = idx/DCAT, c = idx - r*DCAT;
    float val=0.f;
    if (r<nsel){
      int node = start + sel[r];
      if (c<32) val = x1[(size_t)node*32+c];
      else if (c<64) val = x2[(size_t)node*32+(c-32)];
      else if (c<96) val = x3[(size_t)node*32+(c-64)];
      else val = x4[node];
    }
    pg[idx]=val;
  }
}

__global__ __launch_bounds__(128) void k_head(const float* __restrict__ pool,
                       const float* __restrict__ cw5, const float* __restrict__ cb5,
                       const float* __restrict__ cw6, const float* __restrict__ cb6,
                       const float* __restrict__ fw1, const float* __restrict__ fb1,
                       const float* __restrict__ fw2, const float* __restrict__ fb2,
                       float* __restrict__ out){
  __shared__ float P[POOLW];
  __shared__ float o5[16*30];
  __shared__ float m[16*15];
  __shared__ float o6[32*11];
  __shared__ float o1[128];
  __shared__ float logits[10];
  int g=blockIdx.x, t=threadIdx.x;
  const float* pg = pool + (size_t)g*POOLW;
  for (int i=t;i<POOLW;i+=128) P[i]=pg[i];
  __syncthreads();
  for (int i=t;i<480;i+=128){
    int o=i/30, k=i-o*30;
    float acc=cb5[o];
    const float* w=cw5+o*97;
    const float* p=P+k*97;
    for(int c=0;c<97;c++) acc = fmaf(p[c], w[c], acc);
    o5[o*30+k]=fmaxf(acc,0.f);
  }
  __syncthreads();
  for (int i=t;i<240;i+=128){
    int o=i/15,k=i-o*15;
    m[i]=fmaxf(o5[o*30+2*k], o5[o*30+2*k+1]);
  }
  __syncthreads();
  for (int i=t;i<352;i+=128){
    int o2=i/11, k=i-o2*11;
    float acc=cb6[o2];
    const float* w=cw6+o2*80;
    #pragma unroll
    for(int ii=0;ii<16;ii++)
      #pragma unroll
      for(int r=0;r<5;r++)
        acc = fmaf(m[ii*15+k+r], w[ii*5+r], acc);
    o6[o2*11+k]=fmaxf(acc,0.f);
  }
  __syncthreads();
  {
    float acc=fb1[t];
    for(int i=0;i<352;i++) acc = fmaf(o6[i], fw1[i*128+t], acc);
    o1[t]=fmaxf(acc,0.f);
  }
  __syncthreads();
  if (t<10){
    float acc=fb2[t];
    for(int j=0;j<128;j++) acc = fmaf(o1[j], fw2[j*10+t], acc);
    logits[t]=acc;
  }
  __syncthreads();
  if (t==0){
    float mx=logits[0];
    for(int c=1;c<10;c++) mx=fmaxf(mx,logits[c]);
    float s=0.f;
    for(int c=0;c<10;c++) s+=expf(logits[c]-mx);
    float lse=logf(s)+mx;
    for(int c=0;c<10;c++) out[(size_t)g*10+c]=logits[c]-lse;
  }
}

extern "C" void kernel_launch(void* const* d_in, const int* in_sizes, int n_in,
                              void* d_out, int out_size, void* d_ws, size_t ws_size,
                              hipStream_t stream){
  const float* x    = (const float*)d_in[0];
  const int*   ei   = (const int*)d_in[1];
  const int*   batch= (const int*)d_in[2];
  const float* W1=(const float*)d_in[3]; const float* b1=(const float*)d_in[4];
  const float* W2=(const float*)d_in[5]; const float* b2=(const float*)d_in[6];
  const float* W3=(const float*)d_in[7]; const float* b3=(const float*)d_in[8];
  const float* W4=(const float*)d_in[9]; const float* b4=(const float*)d_in[10];
  const float* cw5=(const float*)d_in[11]; const float* cb5=(const float*)d_in[12];
  const float* cw6=(const float*)d_in[13]; const float* cb6=(const float*)d_in[14];
  const float* fw1=(const float*)d_in[15]; const float* fb1=(const float*)d_in[16];
  const float* fw2=(const float*)d_in[17]; const float* fb2=(const float*)d_in[18];
  float* out=(float*)d_out;
  const int* src = ei;
  const int* dst = ei + N_EDGESC;

  char* ws=(char*)d_ws;
  size_t o=0;
  auto alloc=[&](size_t nbytes)->char*{ char* p=ws+o; o += (nbytes+255)&~(size_t)255; return p; };
  float* dis    = (float*)alloc((size_t)N_NODESC*4);
  int*   offs   = (int*)alloc((size_t)N_NODESC*4);
  int*   degc   = (int*)alloc((size_t)N_NODESC*4);
  int*   fptr   = (int*)alloc((size_t)N_NODESC*4);
  int*   bsumA  = (int*)alloc(256*4);
  int*   bsumB  = (int*)alloc(256*4);
  int*   gcount = (int*)alloc((size_t)N_GRAPHSC*4);
  int*   goff   = (int*)alloc((size_t)N_GRAPHSC*4);
  int*   csr    = (int*)alloc((size_t)N_EDGESC*4);
  float* x1 = (float*)alloc((size_t)N_NODESC*32*4);
  float* x2 = (float*)alloc((size_t)N_NODESC*32*4);
  float* x3 = (float*)alloc((size_t)N_NODESC*32*4);
  float* x4 = (float*)alloc((size_t)N_NODESC*4);
  float* hw = (float*)alloc((size_t)N_NODESC*32*4);
  float* pool = hw; /* reuse: pool written only after hw fully consumed */

  hipMemsetAsync(degc, 0, (size_t)N_NODESC*4, stream);
  hipMemsetAsync(gcount, 0, (size_t)N_GRAPHSC*4, stream);

  int gN = (N_NODESC+255)/256;
  int gR = NCHUNK*NRANGE;
  k_count<<<gR,256,0,stream>>>(src,dst,degc);
  k_bhist<<<gN,256,0,stream>>>(batch,gcount);
  int nb1=(N_NODESC+1023)/1024;
  k_scan1<<<nb1,1024,0,stream>>>(degc,offs,bsumA,N_NODESC);
  k_scan2<<<1,256,0,stream>>>(bsumA,nb1);
  k_scan3<<<nb1,1024,0,stream>>>(offs,bsumA,N_NODESC);
  int nb2=(N_GRAPHSC+1023)/1024;
  k_scan1<<<nb2,1024,0,stream>>>(gcount,goff,bsumB,N_GRAPHSC);
  k_scan2<<<1,256,0,stream>>>(bsumB,nb2);
  k_scan3<<<nb2,1024,0,stream>>>(goff,bsumB,N_GRAPHSC);
  k_dis<<<gN,256,0,stream>>>(degc,offs,dis,fptr);
  k_fill<<<gR,256,0,stream>>>(src,dst,fptr,csr);

  int gMM=(N_NODESC+7)/8;
  k_mm<128><<<gMM,256,0,stream>>>(x, W1, dis, hw);
  k_agg<<<gMM,256,0,stream>>>(hw,csr,offs,degc,dis,b1,x1);
  k_mm<32><<<gMM,256,0,stream>>>(x1, W2, dis, hw);
  k_agg<<<gMM,256,0,stream>>>(hw,csr,offs,degc,dis,b2,x2);
  k_mm<32><<<gMM,256,0,stream>>>(x2, W3, dis, hw);
  k_agg<<<gMM,256,0,stream>>>(hw,csr,offs,degc,dis,b3,x3);
  k_mm4<<<gN,256,0,stream>>>(x3, W4, dis, hw);
  k_agg4<<<gN,256,0,stream>>>(hw,csr,offs,degc,dis,b4,x4);

  k_sortpool<<<N_GRAPHSC,256,0,stream>>>(x1,x2,x3,x4,gcount,goff,pool);
  k_head<<<N_GRAPHSC,128,0,stream>>>(pool,cw5,cb5,cw6,cb6,fw1,fb1,fw2,fb2,out);
}

// Round 3
// 844.996 us; speedup vs baseline: 1.4293x; 1.1174x over previous
//
#include <hip/hip_runtime.h>

#define N_NODESC 200000
#define N_EDGESC 3200000
#define N_GRAPHSC 2000
#define NMAXG 256
#define TOPK 30
#define DCAT 97
#define POOLW (TOPK*DCAT) /* 2910 */
#define NRANGE 8
#define RANGEW (N_NODESC/NRANGE) /* 25000 */
#define CHUNKE 8192
#define NCHUNK ((N_EDGESC+CHUNKE-1)/CHUNKE) /* 391 */

__global__ __launch_bounds__(256) void k_count(const int* __restrict__ src, const int* __restrict__ dst, int* __restrict__ cnt){
  int b = blockIdx.x; int r = b & (NRANGE-1); int chunk = b >> 3;
  int lo = r*RANGEW, hi = lo + RANGEW;
  int e0 = chunk*CHUNKE;
  int e1 = e0 + CHUNKE; if (e1 > N_EDGESC) e1 = N_EDGESC;
  for (int base = e0; base < e1; base += 1024){
    int e = base + threadIdx.x*4;
    int4 d4 = *(const int4*)(dst+e);
    int4 s4 = *(const int4*)(src+e);
    if (d4.x>=lo && d4.x<hi && s4.x!=d4.x) atomicAdd(&cnt[d4.x],1);
    if (d4.y>=lo && d4.y<hi && s4.y!=d4.y) atomicAdd(&cnt[d4.y],1);
    if (d4.z>=lo && d4.z<hi && s4.z!=d4.z) atomicAdd(&cnt[d4.z],1);
    if (d4.w>=lo && d4.w<hi && s4.w!=d4.w) atomicAdd(&cnt[d4.w],1);
  }
}

__global__ __launch_bounds__(256) void k_fill(const int* __restrict__ src, const int* __restrict__ dst, int* __restrict__ fptr, int* __restrict__ csr){
  int b = blockIdx.x; int r = b & (NRANGE-1); int chunk = b >> 3;
  int lo = r*RANGEW, hi = lo + RANGEW;
  int e0 = chunk*CHUNKE;
  int e1 = e0 + CHUNKE; if (e1 > N_EDGESC) e1 = N_EDGESC;
  for (int base = e0; base < e1; base += 1024){
    int e = base + threadIdx.x*4;
    int4 d4 = *(const int4*)(dst+e);
    int4 s4 = *(const int4*)(src+e);
    if (d4.x>=lo && d4.x<hi && s4.x!=d4.x){ int p=atomicAdd(&fptr[d4.x],1); csr[p]=s4.x; }
    if (d4.y>=lo && d4.y<hi && s4.y!=d4.y){ int p=atomicAdd(&fptr[d4.y],1); csr[p]=s4.y; }
    if (d4.z>=lo && d4.z<hi && s4.z!=d4.z){ int p=atomicAdd(&fptr[d4.z],1); csr[p]=s4.z; }
    if (d4.w>=lo && d4.w<hi && s4.w!=d4.w){ int p=atomicAdd(&fptr[d4.w],1); csr[p]=s4.w; }
  }
}

__global__ void k_bhist(const int* __restrict__ batch, int* __restrict__ gcount){
  int i = blockIdx.x*256 + threadIdx.x;
  if (i < N_NODESC) atomicAdd(&gcount[batch[i]],1);
}

__global__ __launch_bounds__(1024) void k_scan1(const int* __restrict__ in, int* __restrict__ excl, int* __restrict__ bsum, int n){
  __shared__ int sm[1024];
  int t = threadIdx.x;
  int i = blockIdx.x*1024 + t;
  int v = (i<n)? in[i] : 0;
  sm[t]=v; __syncthreads();
  for (int off=1; off<1024; off<<=1){
    int u = (t>=off)? sm[t-off] : 0;
    __syncthreads();
    sm[t] += u;
    __syncthreads();
  }
  if (i<n) excl[i] = sm[t]-v;
  if (t==1023) bsum[blockIdx.x] = sm[1023];
}

__global__ __launch_bounds__(256) void k_scan2(int* __restrict__ bsum, int nb){
  __shared__ int sm[256];
  int t=threadIdx.x;
  int v = (t<nb)? bsum[t] : 0;
  sm[t]=v; __syncthreads();
  for(int off=1; off<256; off<<=1){
    int u = (t>=off)? sm[t-off] : 0;
    __syncthreads();
    sm[t]+=u;
    __syncthreads();
  }
  if (t<nb) bsum[t] = sm[t]-v;
}

__global__ __launch_bounds__(1024) void k_scan3(int* __restrict__ excl, const int* __restrict__ bsum, int n){
  int i = blockIdx.x*1024 + threadIdx.x;
  if (i<n) excl[i] += bsum[blockIdx.x];
}

/* dis = rsqrt(deg+1); fptr = offs (so atomicAdd gives absolute csr slot) */
__global__ void k_dis(const int* __restrict__ cnt, const int* __restrict__ offs, float* __restrict__ dis, int* __restrict__ fptr){
  int i = blockIdx.x*256+threadIdx.x;
  if (i<N_NODESC){ dis[i] = rsqrtf((float)cnt[i] + 1.0f); fptr[i] = offs[i]; }
}

/* out[r][:] = (X[r] @ W) * dis[r]  — thread-per-row, 32 accumulators.
   W indices are wave-uniform -> compiler emits s_load (scalar pipe). */
template<int KIN>
__global__ __launch_bounds__(256) void k_mm(const float* __restrict__ X, const float* __restrict__ W,
                                            const float* __restrict__ dis, float* __restrict__ out){
  int r = blockIdx.x*256 + threadIdx.x;
  if (r>=N_NODESC) return;
  const float4* xr = (const float4*)(X + (size_t)r*KIN);
  float acc[32];
  #pragma unroll
  for (int f=0;f<32;f++) acc[f]=0.f;
  for (int k4=0;k4<KIN/4;k4++){
    float4 xv = xr[k4];
    const float* w0 = W + k4*4*32;
    #pragma unroll
    for (int f=0;f<32;f++){
      float a = acc[f];
      a = fmaf(xv.x, w0[f],      a);
      a = fmaf(xv.y, w0[32+f],   a);
      a = fmaf(xv.z, w0[64+f],   a);
      a = fmaf(xv.w, w0[96+f],   a);
      acc[f] = a;
    }
  }
  float d = dis[r];
  float4* op = (float4*)(out + (size_t)r*32);
  #pragma unroll
  for (int f4=0;f4<8;f4++)
    op[f4] = make_float4(acc[4*f4]*d, acc[4*f4+1]*d, acc[4*f4+2]*d, acc[4*f4+3]*d);
}

__global__ void k_mm4(const float* __restrict__ X, const float* __restrict__ W, const float* __restrict__ dis, float* __restrict__ out){
  int r = blockIdx.x*256+threadIdx.x;
  if (r>=N_NODESC) return;
  const float4* xr = (const float4*)(X + (size_t)r*32);
  float acc=0.f;
  #pragma unroll
  for (int k4=0;k4<8;k4++){
    float4 xv = xr[k4];
    acc = fmaf(xv.x, W[k4*4+0], acc);
    acc = fmaf(xv.y, W[k4*4+1], acc);
    acc = fmaf(xv.z, W[k4*4+2], acc);
    acc = fmaf(xv.w, W[k4*4+3], acc);
  }
  out[r]=acc*dis[r];
}

/* x_out[n][f] = tanh( dis[n]*(sum_src hws[src][f] + hws[n][f]) + b[f] ) */
__global__ __launch_bounds__(256) void k_agg(const float* __restrict__ hws, const int* __restrict__ csr,
                      const int* __restrict__ off, const int* __restrict__ cnt,
                      const float* __restrict__ dis, const float* __restrict__ bias,
                      float* __restrict__ out){
  int t = blockIdx.x*256 + threadIdx.x;
  int n = t>>5;
  if (n>=N_NODESC) return;
  int f = t&31;
  int beg = off[n], c = cnt[n];
  float acc0=0.f, acc1=0.f;
  int e=0;
  for (; e+1<c; e+=2){
    int s0 = csr[beg+e];
    int s1 = csr[beg+e+1];
    acc0 += hws[(size_t)s0*32+f];
    acc1 += hws[(size_t)s1*32+f];
  }
  if (e<c) acc0 += hws[(size_t)csr[beg+e]*32+f];
  float dn = dis[n];
  float v = dn*(acc0+acc1+hws[(size_t)n*32+f]) + bias[f];
  out[(size_t)n*32+f] = tanhf(v);
}

__global__ void k_agg4(const float* __restrict__ hws4, const int* __restrict__ csr,
                       const int* __restrict__ off, const int* __restrict__ cnt,
                       const float* __restrict__ dis, const float* __restrict__ b4,
                       float* __restrict__ x4){
  int n = blockIdx.x*256+threadIdx.x;
  if (n>=N_NODESC) return;
  int beg=off[n], c=cnt[n];
  float acc0=0.f, acc1=0.f;
  int e=0;
  for (; e+1<c; e+=2){ acc0 += hws4[csr[beg+e]]; acc1 += hws4[csr[beg+e+1]]; }
  if (e<c) acc0 += hws4[csr[beg+e]];
  float dn=dis[n];
  x4[n] = tanhf(dn*(acc0+acc1+hws4[n]) + b4[0]);
}

__global__ __launch_bounds__(256) void k_sortpool(const float* __restrict__ x1,const float* __restrict__ x2,const float* __restrict__ x3,const float* __restrict__ x4,
                           const int* __restrict__ gcount, const int* __restrict__ goff, float* __restrict__ pool){
  __shared__ float vals[NMAXG];
  __shared__ int sel[TOPK];
  int g = blockIdx.x;
  int start = goff[g];
  int cntg = gcount[g]; if (cntg>NMAXG) cntg=NMAXG;
  int t = threadIdx.x;
  float v = 0.f;
  if (t<cntg) v = x4[start+t];
  vals[t] = v;
  __syncthreads();
  if (t<cntg){
    int rank=0;
    for (int j=0;j<cntg;j++){
      float vj=vals[j];
      rank += (vj>v) || (vj==v && j<t);
    }
    if (rank<TOPK) sel[rank]=t;
  }
  __syncthreads();
  int nsel = cntg<TOPK?cntg:TOPK;
  float* pg = pool + (size_t)g*POOLW;
  for (int idx=t; idx<POOLW; idx+=256){
    int r = idx/DCAT, c = idx - r*DCAT;
    float val=0.f;
    if (r<nsel){
      int node = start + sel[r];
      if (c<32) val = x1[(size_t)node*32+c];
      else if (c<64) val = x2[(size_t)node*32+(c-32)];
      else if (c<96) val = x3[(size_t)node*32+(c-64)];
      else val = x4[node];
    }
    pg[idx]=val;
  }
}

__global__ __launch_bounds__(128) void k_head(const float* __restrict__ pool,
                       const float* __restrict__ cw5, const float* __restrict__ cb5,
                       const float* __restrict__ cw6, const float* __restrict__ cb6,
                       const float* __restrict__ fw1, const float* __restrict__ fb1,
                       const float* __restrict__ fw2, const float* __restrict__ fb2,
                       float* __restrict__ out){
  __shared__ float P[POOLW];
  __shared__ float o5[16*30];
  __shared__ float m[16*15];
  __shared__ float o6[32*11];
  __shared__ float o1[128];
  __shared__ float logits[10];
  int g=blockIdx.x, t=threadIdx.x;
  const float* pg = pool + (size_t)g*POOLW;
  for (int i=t;i<POOLW;i+=128) P[i]=pg[i];
  __syncthreads();
  for (int i=t;i<480;i+=128){
    int o=i/30, k=i-o*30;
    float acc=cb5[o];
    const float* w=cw5+o*97;
    const float* p=P+k*97;
    for(int c=0;c<97;c++) acc = fmaf(p[c], w[c], acc);
    o5[o*30+k]=fmaxf(acc,0.f);
  }
  __syncthreads();
  for (int i=t;i<240;i+=128){
    int o=i/15,k=i-o*15;
    m[i]=fmaxf(o5[o*30+2*k], o5[o*30+2*k+1]);
  }
  __syncthreads();
  for (int i=t;i<352;i+=128){
    int o2=i/11, k=i-o2*11;
    float acc=cb6[o2];
    const float* w=cw6+o2*80;
    #pragma unroll
    for(int ii=0;ii<16;ii++)
      #pragma unroll
      for(int r=0;r<5;r++)
        acc = fmaf(m[ii*15+k+r], w[ii*5+r], acc);
    o6[o2*11+k]=fmaxf(acc,0.f);
  }
  __syncthreads();
  {
    float acc=fb1[t];
    for(int i=0;i<352;i++) acc = fmaf(o6[i], fw1[i*128+t], acc);
    o1[t]=fmaxf(acc,0.f);
  }
  __syncthreads();
  if (t<10){
    float acc=fb2[t];
    for(int j=0;j<128;j++) acc = fmaf(o1[j], fw2[j*10+t], acc);
    logits[t]=acc;
  }
  __syncthreads();
  if (t==0){
    float mx=logits[0];
    for(int c=1;c<10;c++) mx=fmaxf(mx,logits[c]);
    float s=0.f;
    for(int c=0;c<10;c++) s+=expf(logits[c]-mx);
    float lse=logf(s)+mx;
    for(int c=0;c<10;c++) out[(size_t)g*10+c]=logits[c]-lse;
  }
}

extern "C" void kernel_launch(void* const* d_in, const int* in_sizes, int n_in,
                              void* d_out, int out_size, void* d_ws, size_t ws_size,
                              hipStream_t stream){
  const float* x    = (const float*)d_in[0];
  const int*   ei   = (const int*)d_in[1];
  const int*   batch= (const int*)d_in[2];
  const float* W1=(const float*)d_in[3]; const float* b1=(const float*)d_in[4];
  const float* W2=(const float*)d_in[5]; const float* b2=(const float*)d_in[6];
  const float* W3=(const float*)d_in[7]; const float* b3=(const float*)d_in[8];
  const float* W4=(const float*)d_in[9]; const float* b4=(const float*)d_in[10];
  const float* cw5=(const float*)d_in[11]; const float* cb5=(const float*)d_in[12];
  const float* cw6=(const float*)d_in[13]; const float* cb6=(const float*)d_in[14];
  const float* fw1=(const float*)d_in[15]; const float* fb1=(const float*)d_in[16];
  const float* fw2=(const float*)d_in[17]; const float* fb2=(const float*)d_in[18];
  float* out=(float*)d_out;
  const int* src = ei;
  const int* dst = ei + N_EDGESC;

  char* ws=(char*)d_ws;
  size_t o=0;
  auto alloc=[&](size_t nbytes)->char*{ char* p=ws+o; o += (nbytes+255)&~(size_t)255; return p; };
  float* dis    = (float*)alloc((size_t)N_NODESC*4);
  int*   offs   = (int*)alloc((size_t)N_NODESC*4);
  int*   degc   = (int*)alloc((size_t)N_NODESC*4);
  int*   fptr   = (int*)alloc((size_t)N_NODESC*4);
  int*   bsumA  = (int*)alloc(256*4);
  int*   bsumB  = (int*)alloc(256*4);
  int*   gcount = (int*)alloc((size_t)N_GRAPHSC*4);
  int*   goff   = (int*)alloc((size_t)N_GRAPHSC*4);
  int*   csr    = (int*)alloc((size_t)N_EDGESC*4);
  float* x1 = (float*)alloc((size_t)N_NODESC*32*4);
  float* x2 = (float*)alloc((size_t)N_NODESC*32*4);
  float* x3 = (float*)alloc((size_t)N_NODESC*32*4);
  float* x4 = (float*)alloc((size_t)N_NODESC*4);
  float* hw = (float*)alloc((size_t)N_NODESC*32*4);
  float* pool = hw; /* reuse: pool written only after hw fully consumed */

  hipMemsetAsync(degc, 0, (size_t)N_NODESC*4, stream);
  hipMemsetAsync(gcount, 0, (size_t)N_GRAPHSC*4, stream);

  int gN = (N_NODESC+255)/256;
  int gR = NCHUNK*NRANGE;
  k_count<<<gR,256,0,stream>>>(src,dst,degc);
  k_bhist<<<gN,256,0,stream>>>(batch,gcount);
  int nb1=(N_NODESC+1023)/1024;
  k_scan1<<<nb1,1024,0,stream>>>(degc,offs,bsumA,N_NODESC);
  k_scan2<<<1,256,0,stream>>>(bsumA,nb1);
  k_scan3<<<nb1,1024,0,stream>>>(offs,bsumA,N_NODESC);
  int nb2=(N_GRAPHSC+1023)/1024;
  k_scan1<<<nb2,1024,0,stream>>>(gcount,goff,bsumB,N_GRAPHSC);
  k_scan2<<<1,256,0,stream>>>(bsumB,nb2);
  k_scan3<<<nb2,1024,0,stream>>>(goff,bsumB,N_GRAPHSC);
  k_dis<<<gN,256,0,stream>>>(degc,offs,dis,fptr);
  k_fill<<<gR,256,0,stream>>>(src,dst,fptr,csr);

  int gMM=(N_NODESC+7)/8;
  k_mm<128><<<gN,256,0,stream>>>(x, W1, dis, hw);
  k_agg<<<gMM,256,0,stream>>>(hw,csr,offs,degc,dis,b1,x1);
  k_mm<32><<<gN,256,0,stream>>>(x1, W2, dis, hw);
  k_agg<<<gMM,256,0,stream>>>(hw,csr,offs,degc,dis,b2,x2);
  k_mm<32><<<gN,256,0,stream>>>(x2, W3, dis, hw);
  k_agg<<<gMM,256,0,stream>>>(hw,csr,offs,degc,dis,b3,x3);
  k_mm4<<<gN,256,0,stream>>>(x3, W4, dis, hw);
  k_agg4<<<gN,256,0,stream>>>(hw,csr,offs,degc,dis,b4,x4);

  k_sortpool<<<N_GRAPHSC,256,0,stream>>>(x1,x2,x3,x4,gcount,goff,pool);
  k_head<<<N_GRAPHSC,128,0,stream>>>(pool,cw5,cb5,cw6,cb6,fw1,fb1,fw2,fb2,out);
}

// Round 5
// 827.032 us; speedup vs baseline: 1.4604x; 1.0217x over previous
//
#include <hip/hip_runtime.h>

#define N_NODESC 200000
#define N_EDGESC 3200000
#define N_GRAPHSC 2000
#define NMAXG 256
#define TOPK 30
#define DCAT 97
#define POOLW (TOPK*DCAT) /* 2910 */
#define NRANGE 8
#define RANGEW (N_NODESC/NRANGE) /* 25000 */
#define CHUNKE 8192
#define NCHUNK ((N_EDGESC+CHUNKE-1)/CHUNKE) /* 391 */

typedef int  iv4 __attribute__((ext_vector_type(4)));
typedef float fv4 __attribute__((ext_vector_type(4)));

__global__ __launch_bounds__(256) void k_count(const int* __restrict__ src, const int* __restrict__ dst, int* __restrict__ cnt){
  int e = (blockIdx.x*256 + threadIdx.x)*4;
  if (e >= N_EDGESC) return;
  iv4 d4 = __builtin_nontemporal_load((const iv4*)(dst+e));
  iv4 s4 = __builtin_nontemporal_load((const iv4*)(src+e));
  if (s4.x!=d4.x) atomicAdd(&cnt[d4.x],1);
  if (s4.y!=d4.y) atomicAdd(&cnt[d4.y],1);
  if (s4.z!=d4.z) atomicAdd(&cnt[d4.z],1);
  if (s4.w!=d4.w) atomicAdd(&cnt[d4.w],1);
}

__global__ __launch_bounds__(256) void k_fill(const int* __restrict__ src, const int* __restrict__ dst, int* __restrict__ fptr, int* __restrict__ csr){
  int b = blockIdx.x; int r = b & (NRANGE-1); int chunk = b >> 3;
  int lo = r*RANGEW, hi = lo + RANGEW;
  int e0 = chunk*CHUNKE;
  int e1 = e0 + CHUNKE; if (e1 > N_EDGESC) e1 = N_EDGESC;
  for (int base = e0; base < e1; base += 1024){
    int e = base + threadIdx.x*4;
    iv4 d4 = __builtin_nontemporal_load((const iv4*)(dst+e));
    iv4 s4 = __builtin_nontemporal_load((const iv4*)(src+e));
    if (d4.x>=lo && d4.x<hi && s4.x!=d4.x){ int p=atomicAdd(&fptr[d4.x],1); csr[p]=s4.x; }
    if (d4.y>=lo && d4.y<hi && s4.y!=d4.y){ int p=atomicAdd(&fptr[d4.y],1); csr[p]=s4.y; }
    if (d4.z>=lo && d4.z<hi && s4.z!=d4.z){ int p=atomicAdd(&fptr[d4.z],1); csr[p]=s4.z; }
    if (d4.w>=lo && d4.w<hi && s4.w!=d4.w){ int p=atomicAdd(&fptr[d4.w],1); csr[p]=s4.w; }
  }
}

__global__ void k_bhist(const int* __restrict__ batch, int* __restrict__ gcount){
  int i = blockIdx.x*256 + threadIdx.x;
  if (i < N_NODESC) atomicAdd(&gcount[batch[i]],1);
}

__global__ __launch_bounds__(1024) void k_scan1(const int* __restrict__ in, int* __restrict__ excl, int* __restrict__ bsum, int n){
  __shared__ int sm[1024];
  int t = threadIdx.x;
  int i = blockIdx.x*1024 + t;
  int v = (i<n)? in[i] : 0;
  sm[t]=v; __syncthreads();
  for (int off=1; off<1024; off<<=1){
    int u = (t>=off)? sm[t-off] : 0;
    __syncthreads();
    sm[t] += u;
    __syncthreads();
  }
  if (i<n) excl[i] = sm[t]-v;
  if (t==1023) bsum[blockIdx.x] = sm[1023];
}

__global__ __launch_bounds__(256) void k_scan2(int* __restrict__ bsum, int nb){
  __shared__ int sm[256];
  int t=threadIdx.x;
  int v = (t<nb)? bsum[t] : 0;
  sm[t]=v; __syncthreads();
  for(int off=1; off<256; off<<=1){
    int u = (t>=off)? sm[t-off] : 0;
    __syncthreads();
    sm[t]+=u;
    __syncthreads();
  }
  if (t<nb) bsum[t] = sm[t]-v;
}

__global__ __launch_bounds__(1024) void k_scan3(int* __restrict__ excl, const int* __restrict__ bsum, int n){
  int i = blockIdx.x*1024 + threadIdx.x;
  if (i<n) excl[i] += bsum[blockIdx.x];
}

/* dis = rsqrt(deg+1); fptr = offs (so atomicAdd gives absolute csr slot) */
__global__ void k_dis(const int* __restrict__ cnt, const int* __restrict__ offs, float* __restrict__ dis, int* __restrict__ fptr){
  int i = blockIdx.x*256+threadIdx.x;
  if (i<N_NODESC){ dis[i] = rsqrtf((float)cnt[i] + 1.0f); fptr[i] = offs[i]; }
}

/* out[r][:] = (X[r] @ W) * dis[r]  — thread-per-row, 32 accumulators.
   W indices are wave-uniform -> scalar loads. X streamed non-temporally. */
template<int KIN>
__global__ __launch_bounds__(256) void k_mm(const float* __restrict__ X, const float* __restrict__ W,
                                            const float* __restrict__ dis, float* __restrict__ out){
  int r = blockIdx.x*256 + threadIdx.x;
  if (r>=N_NODESC) return;
  const fv4* xr = (const fv4*)(X + (size_t)r*KIN);
  float acc[32];
  #pragma unroll
  for (int f=0;f<32;f++) acc[f]=0.f;
  for (int k4=0;k4<KIN/4;k4++){
    fv4 xv = __builtin_nontemporal_load(xr+k4);
    const float* w0 = W + k4*4*32;
    #pragma unroll
    for (int f=0;f<32;f++){
      float a = acc[f];
      a = fmaf(xv.x, w0[f],      a);
      a = fmaf(xv.y, w0[32+f],   a);
      a = fmaf(xv.z, w0[64+f],   a);
      a = fmaf(xv.w, w0[96+f],   a);
      acc[f] = a;
    }
  }
  float d = dis[r];
  float4* op = (float4*)(out + (size_t)r*32);
  #pragma unroll
  for (int f4=0;f4<8;f4++)
    op[f4] = make_float4(acc[4*f4]*d, acc[4*f4+1]*d, acc[4*f4+2]*d, acc[4*f4+3]*d);
}

__global__ void k_mm4(const float* __restrict__ X, const float* __restrict__ W, const float* __restrict__ dis, float* __restrict__ out){
  int r = blockIdx.x*256+threadIdx.x;
  if (r>=N_NODESC) return;
  const float4* xr = (const float4*)(X + (size_t)r*32);
  float acc=0.f;
  #pragma unroll
  for (int k4=0;k4<8;k4++){
    float4 xv = xr[k4];
    acc = fmaf(xv.x, W[k4*4+0], acc);
    acc = fmaf(xv.y, W[k4*4+1], acc);
    acc = fmaf(xv.z, W[k4*4+2], acc);
    acc = fmaf(xv.w, W[k4*4+3], acc);
  }
  out[r]=acc*dis[r];
}

/* x_out[n][f] = tanh( dis[n]*(sum_src hws[src][f] + hws[n][f]) + b[f] )
   32 lanes per node; CSR indices batch-loaded 32-wide then shfl-broadcast. */
__global__ __launch_bounds__(256) void k_agg(const float* __restrict__ hws, const int* __restrict__ csr,
                      const int* __restrict__ off, const int* __restrict__ cnt,
                      const float* __restrict__ dis, const float* __restrict__ bias,
                      float* __restrict__ out){
  int t = blockIdx.x*256 + threadIdx.x;
  int n = t>>5;
  if (n>=N_NODESC) return;
  int f = t&31;
  int beg = off[n], c = cnt[n];
  float a0=0.f,a1=0.f,a2=0.f,a3=0.f;
  for (int base=0; base<c; base+=32){
    int m = c-base; if (m>32) m=32;
    int idx = (f<m)? csr[beg+base+f] : 0;
    int j=0;
    for (; j+4<=m; j+=4){
      int s0=__shfl(idx,j,32), s1=__shfl(idx,j+1,32),
          s2=__shfl(idx,j+2,32), s3=__shfl(idx,j+3,32);
      float v0=hws[(size_t)s0*32+f];
      float v1=hws[(size_t)s1*32+f];
      float v2=hws[(size_t)s2*32+f];
      float v3=hws[(size_t)s3*32+f];
      a0+=v0; a1+=v1; a2+=v2; a3+=v3;
    }
    for (; j<m; j++){
      int s0=__shfl(idx,j,32);
      a0 += hws[(size_t)s0*32+f];
    }
  }
  float dn = dis[n];
  float v = dn*(((a0+a1)+(a2+a3))+hws[(size_t)n*32+f]) + bias[f];
  out[(size_t)n*32+f] = tanhf(v);
}

__global__ void k_agg4(const float* __restrict__ hws4, const int* __restrict__ csr,
                       const int* __restrict__ off, const int* __restrict__ cnt,
                       const float* __restrict__ dis, const float* __restrict__ b4,
                       float* __restrict__ x4){
  int n = blockIdx.x*256+threadIdx.x;
  if (n>=N_NODESC) return;
  int beg=off[n], c=cnt[n];
  float a0=0.f,a1=0.f,a2=0.f,a3=0.f;
  int e=0;
  for (; e+4<=c; e+=4){
    int s0=csr[beg+e], s1=csr[beg+e+1], s2=csr[beg+e+2], s3=csr[beg+e+3];
    a0+=hws4[s0]; a1+=hws4[s1]; a2+=hws4[s2]; a3+=hws4[s3];
  }
  for (; e<c; e++) a0+=hws4[csr[beg+e]];
  float dn=dis[n];
  x4[n] = tanhf(dn*(((a0+a1)+(a2+a3))+hws4[n]) + b4[0]);
}

__global__ __launch_bounds__(256) void k_sortpool(const float* __restrict__ x1,const float* __restrict__ x2,const float* __restrict__ x3,const float* __restrict__ x4,
                           const int* __restrict__ gcount, const int* __restrict__ goff, float* __restrict__ pool){
  __shared__ float vals[NMAXG];
  __shared__ int sel[TOPK];
  int g = blockIdx.x;
  int start = goff[g];
  int cntg = gcount[g]; if (cntg>NMAXG) cntg=NMAXG;
  int t = threadIdx.x;
  float v = 0.f;
  if (t<cntg) v = x4[start+t];
  vals[t] = v;
  __syncthreads();
  if (t<cntg){
    int rank=0;
    for (int j=0;j<cntg;j++){
      float vj=vals[j];
      rank += (vj>v) || (vj==v && j<t);
    }
    if (rank<TOPK) sel[rank]=t;
  }
  __syncthreads();
  int nsel = cntg<TOPK?cntg:TOPK;
  float* pg = pool + (size_t)g*POOLW;
  for (int idx=t; idx<POOLW; idx+=256){
    int r = idx/DCAT, c = idx - r*DCAT;
    float val=0.f;
    if (r<nsel){
      int node = start + sel[r];
      if (c<32) val = x1[(size_t)node*32+c];
      else if (c<64) val = x2[(size_t)node*32+(c-32)];
      else if (c<96) val = x3[(size_t)node*32+(c-64)];
      else val = x4[node];
    }
    pg[idx]=val;
  }
}

__global__ __launch_bounds__(128) void k_head(const float* __restrict__ pool,
                       const float* __restrict__ cw5, const float* __restrict__ cb5,
                       const float* __restrict__ cw6, const float* __restrict__ cb6,
                       const float* __restrict__ fw1, const float* __restrict__ fb1,
                       const float* __restrict__ fw2, const float* __restrict__ fb2,
                       float* __restrict__ out){
  __shared__ float P[POOLW];
  __shared__ float o5[16*30];
  __shared__ float m[16*15];
  __shared__ float o6[32*11];
  __shared__ float o1[128];
  __shared__ float logits[10];
  int g=blockIdx.x, t=threadIdx.x;
  const float* pg = pool + (size_t)g*POOLW;
  for (int i=t;i<POOLW;i+=128) P[i]=pg[i];
  __syncthreads();
  for (int i=t;i<480;i+=128){
    int o=i/30, k=i-o*30;
    float acc=cb5[o];
    const float* w=cw5+o*97;
    const float* p=P+k*97;
    for(int c=0;c<97;c++) acc = fmaf(p[c], w[c], acc);
    o5[o*30+k]=fmaxf(acc,0.f);
  }
  __syncthreads();
  for (int i=t;i<240;i+=128){
    int o=i/15,k=i-o*15;
    m[i]=fmaxf(o5[o*30+2*k], o5[o*30+2*k+1]);
  }
  __syncthreads();
  for (int i=t;i<352;i+=128){
    int o2=i/11, k=i-o2*11;
    float acc=cb6[o2];
    const float* w=cw6+o2*80;
    #pragma unroll
    for(int ii=0;ii<16;ii++)
      #pragma unroll
      for(int r=0;r<5;r++)
        acc = fmaf(m[ii*15+k+r], w[ii*5+r], acc);
    o6[o2*11+k]=fmaxf(acc,0.f);
  }
  __syncthreads();
  {
    float acc=fb1[t];
    for(int i=0;i<352;i++) acc = fmaf(o6[i], fw1[i*128+t], acc);
    o1[t]=fmaxf(acc,0.f);
  }
  __syncthreads();
  if (t<10){
    float acc=fb2[t];
    for(int j=0;j<128;j++) acc = fmaf(o1[j], fw2[j*10+t], acc);
    logits[t]=acc;
  }
  __syncthreads();
  if (t==0){
    float mx=logits[0];
    for(int c=1;c<10;c++) mx=fmaxf(mx,logits[c]);
    float s=0.f;
    for(int c=0;c<10;c++) s+=expf(logits[c]-mx);
    float lse=logf(s)+mx;
    for(int c=0;c<10;c++) out[(size_t)g*10+c]=logits[c]-lse;
  }
}

extern "C" void kernel_launch(void* const* d_in, const int* in_sizes, int n_in,
                              void* d_out, int out_size, void* d_ws, size_t ws_size,
                              hipStream_t stream){
  const float* x    = (const float*)d_in[0];
  const int*   ei   = (const int*)d_in[1];
  const int*   batch= (const int*)d_in[2];
  const float* W1=(const float*)d_in[3]; const float* b1=(const float*)d_in[4];
  const float* W2=(const float*)d_in[5]; const float* b2=(const float*)d_in[6];
  const float* W3=(const float*)d_in[7]; const float* b3=(const float*)d_in[8];
  const float* W4=(const float*)d_in[9]; const float* b4=(const float*)d_in[10];
  const float* cw5=(const float*)d_in[11]; const float* cb5=(const float*)d_in[12];
  const float* cw6=(const float*)d_in[13]; const float* cb6=(const float*)d_in[14];
  const float* fw1=(const float*)d_in[15]; const float* fb1=(const float*)d_in[16];
  const float* fw2=(const float*)d_in[17]; const float* fb2=(const float*)d_in[18];
  float* out=(float*)d_out;
  const int* src = ei;
  const int* dst = ei + N_EDGESC;

  char* ws=(char*)d_ws;
  size_t o=0;
  auto alloc=[&](size_t nbytes)->char*{ char* p=ws+o; o += (nbytes+255)&~(size_t)255; return p; };
  float* dis    = (float*)alloc((size_t)N_NODESC*4);
  int*   offs   = (int*)alloc((size_t)N_NODESC*4);
  int*   degc   = (int*)alloc((size_t)N_NODESC*4);
  int*   fptr   = (int*)alloc((size_t)N_NODESC*4);
  int*   bsumA  = (int*)alloc(256*4);
  int*   bsumB  = (int*)alloc(256*4);
  int*   gcount = (int*)alloc((size_t)N_GRAPHSC*4);
  int*   goff   = (int*)alloc((size_t)N_GRAPHSC*4);
  int*   csr    = (int*)alloc((size_t)N_EDGESC*4);
  float* x1 = (float*)alloc((size_t)N_NODESC*32*4);
  float* x2 = (float*)alloc((size_t)N_NODESC*32*4);
  float* x3 = (float*)alloc((size_t)N_NODESC*32*4);
  float* x4 = (float*)alloc((size_t)N_NODESC*4);
  float* hw = (float*)alloc((size_t)N_NODESC*32*4);
  float* pool = hw; /* reuse: pool written only after hw fully consumed */

  (void)hipMemsetAsync(degc, 0, (size_t)N_NODESC*4, stream);
  (void)hipMemsetAsync(gcount, 0, (size_t)N_GRAPHSC*4, stream);

  int gN = (N_NODESC+255)/256;
  int gR = NCHUNK*NRANGE;
  int gE4 = (N_EDGESC/4 + 255)/256;
  k_count<<<gE4,256,0,stream>>>(src,dst,degc);
  k_bhist<<<gN,256,0,stream>>>(batch,gcount);
  int nb1=(N_NODESC+1023)/1024;
  k_scan1<<<nb1,1024,0,stream>>>(degc,offs,bsumA,N_NODESC);
  k_scan2<<<1,256,0,stream>>>(bsumA,nb1);
  k_scan3<<<nb1,1024,0,stream>>>(offs,bsumA,N_NODESC);
  int nb2=(N_GRAPHSC+1023)/1024;
  k_scan1<<<nb2,1024,0,stream>>>(gcount,goff,bsumB,N_GRAPHSC);
  k_scan2<<<1,256,0,stream>>>(bsumB,nb2);
  k_scan3<<<nb2,1024,0,stream>>>(goff,bsumB,N_GRAPHSC);
  k_dis<<<gN,256,0,stream>>>(degc,offs,dis,fptr);
  k_fill<<<gR,256,0,stream>>>(src,dst,fptr,csr);

  int gMM=(N_NODESC+7)/8;
  k_mm<128><<<gN,256,0,stream>>>(x, W1, dis, hw);
  k_agg<<<gMM,256,0,stream>>>(hw,csr,offs,degc,dis,b1,x1);
  k_mm<32><<<gN,256,0,stream>>>(x1, W2, dis, hw);
  k_agg<<<gMM,256,0,stream>>>(hw,csr,offs,degc,dis,b2,x2);
  k_mm<32><<<gN,256,0,stream>>>(x2, W3, dis, hw);
  k_agg<<<gMM,256,0,stream>>>(hw,csr,offs,degc,dis,b3,x3);
  k_mm4<<<gN,256,0,stream>>>(x3, W4, dis, hw);
  k_agg4<<<gN,256,0,stream>>>(hw,csr,offs,degc,dis,b4,x4);

  k_sortpool<<<N_GRAPHSC,256,0,stream>>>(x1,x2,x3,x4,gcount,goff,pool);
  k_head<<<N_GRAPHSC,128,0,stream>>>(pool,cw5,cb5,cw6,cb6,fw1,fb1,fw2,fb2,out);
}